// Round 3
// baseline (303.694 us; speedup 1.0000x reference)
//
#include <hip/hip_runtime.h>

#define BINS   10
#define CSHIFT 26
#define QMASK  0x03FFFFFFu
#define QSCALE 2097152.0f        // 2^21 quanta per loss unit
#define QLN2   1453635.25f       // ln2 * 2^21: q = round(log2(1+em) * QLN2)
#define GRID   1536              // 6 blocks/CU co-resident (24 KB LDS each)
#define TPB    256
#define TILE   1024              // samples per tile: 8 KB outs + 4 KB tgt

// ws layout: per bin b (cache-line padded): float qsum @ 128*b, u32 cnt @ 128*b+64.
// Ticket counter @ byte 1280. Values are CUMULATIVE over bins; last block diffs.
// ws re-poisoned 0xAA each replay -> zero kernel each launch.

__global__ void ghm_zero_ws(unsigned* ws) {
    if (threadIdx.x < 321) ws[threadIdx.x] = 0u;   // 10*128 B slots + ticket
}

// Async global->LDS DMA, 16 B/lane. LDS dest = wave-uniform base + lane*16.
__device__ __forceinline__ void gld_lds16(const void* g, void* l) {
    __builtin_amdgcn_global_load_lds(
        (const __attribute__((address_space(1))) void*)g,
        (__attribute__((address_space(3))) void*)l, 16, 0, 0);
}

// bin b <=> D[b+1] < d <= D[b], D[b] = ln(20/b - 1); cumulative A[b] over d>Th[b].
// Packed u32: count in [31:26], quantized loss sum in [25:0].
// Per-thread bounds (<=44 samples/thread): count<=44<64; q<=44*1.45M=64M<2^26. OK.
__device__ __forceinline__ void proc1(float o0, float o1, int t, unsigned* A) {
    const float Th[BINS] = {
        2.9444390f, 2.1972246f, 1.7346011f, 1.3862944f, 1.0986123f,
        0.8472979f, 0.6190392f, 0.4054651f, 0.2006707f, 0.0f };
    float s = o0 - o1;
    float d = __int_as_float(__float_as_int(s) ^ (t << 31));  // target - other
    float em = __expf(-d);
    float qf = fmaf(__log2f(1.0f + em), QLN2, 0.5f);  // round(loss * 2^21)
    unsigned val = (unsigned)qf + (1u << CSHIFT);     // d<=0 lanes: masked below
    #pragma unroll
    for (int b = 0; b < BINS; ++b)
        A[b] += (d > Th[b]) ? val : 0u;
}

__global__ __launch_bounds__(TPB, 6)
void ghm_main(const float* __restrict__ outs,     // [n,2] f32
              const int*   __restrict__ tgt,      // [n]   i32
              unsigned char* __restrict__ ws,
              const float* __restrict__ acc_sum,  // [10] f32
              float*       __restrict__ out,
              int n) {
    // Staging buffers union'd with epilogue scratch (never live together).
    __shared__ union {
        struct {
            unsigned char o[2][TILE * 8];      // 2 x 8 KB, global byte order
            unsigned char t[2][TILE * 4];      // 2 x 4 KB
        } st;
        struct {
            unsigned h[BINS][256];             // 10 KB
            unsigned c[BINS][16];
            float    q[BINS][16];
        } ep;
    } sh;                                      // 24 KB

    const int tid  = threadIdx.x;
    const int lane = tid & 63;
    const int wv   = tid >> 6;

    unsigned A[BINS];
    #pragma unroll
    for (int b = 0; b < BINS; ++b) A[b] = 0u;

    const int ntiles = n >> 10;                // full 1024-sample tiles

    // Stage tile -> buffer pb: per wave 2x1KB outs + 1x1KB tgt DMA issues.
    const char* outs_b = (const char*)outs;
    const char* tgt_b  = (const char*)tgt;
    #define STAGE(tile, pb)                                                     \
        do {                                                                    \
            const char* go = outs_b + ((size_t)(tile) << 13) + (wv << 11)       \
                             + (lane << 4);                                     \
            char*       lo = (char*)sh.st.o[pb] + (wv << 11);                   \
            gld_lds16(go, lo);                                                  \
            gld_lds16(go + 1024, lo + 1024);                                    \
            const char* gt = tgt_b + ((size_t)(tile) << 12) + (wv << 10)        \
                             + (lane << 4);                                     \
            gld_lds16(gt, (char*)sh.st.t[pb] + (wv << 10));                     \
        } while (0)

    int t  = blockIdx.x;
    int pb = 0;
    if (t < ntiles) STAGE(t, 0);
    __syncthreads();                           // tile t resident

    for (; t < ntiles; t += gridDim.x) {
        int tn = t + gridDim.x;
        if (tn < ntiles) STAGE(tn, pb ^ 1);    // async: overlaps consume below

        const float4* o4 = (const float4*)sh.st.o[pb];
        const int4*   t4 = (const int4*)sh.st.t[pb];
        float4 a  = o4[2 * tid];
        float4 bq = o4[2 * tid + 1];
        int4   tv = t4[tid];
        proc1(a.x,  a.y,  tv.x, A);
        proc1(a.z,  a.w,  tv.y, A);
        proc1(bq.x, bq.y, tv.z, A);
        proc1(bq.z, bq.w, tv.w, A);

        __syncthreads();                       // drains next-tile DMA too
        pb ^= 1;
    }

    // tail samples (n % 1024; zero at N=2^24) — block 0, direct from global
    int rem = ntiles << 10;
    if (blockIdx.x == 0) {
        for (int s = rem + tid; s < n; s += TPB)
            proc1(outs[2 * s], outs[2 * s + 1], tgt[s], A);
    }

    // ---- epilogue: dump packed regs, tree-reduce, 20 padded atomics/block ----
    __syncthreads();                           // staging reads fully done
    #pragma unroll
    for (int b = 0; b < BINS; ++b) sh.ep.h[b][tid] = A[b];
    __syncthreads();

    if (tid < 16 * BINS) {
        int bin  = tid >> 4;
        int part = tid & 15;
        unsigned c = 0, q = 0;                 // q <= 16*64M ~ 1.0e9 < 2^32
        #pragma unroll
        for (int j = 0; j < 16; ++j) {
            unsigned v = sh.ep.h[bin][j * 16 + part];
            c += v >> CSHIFT;
            q += v & QMASK;
        }
        sh.ep.c[bin][part] = c;
        sh.ep.q[bin][part] = (float)q;
    }
    __syncthreads();
    if (tid < BINS) {
        unsigned c = 0; float q = 0.0f;
        #pragma unroll
        for (int j = 0; j < 16; ++j) { c += sh.ep.c[tid][j]; q += sh.ep.q[tid][j]; }
        if (c) {                               // each bin on its own cache line
            atomicAdd((unsigned*)(ws + 128 * tid + 64), c);
            atomicAdd((float*)   (ws + 128 * tid),      q * (1.0f / QSCALE));
        }
    }

    // ---- fused finalization: last block to arrive computes the output ----
    // Barrier drains the atomics (s_waitcnt vmcnt(0) before s_barrier), so the
    // ticket RMW (acq_rel, agent scope) is ordered after this block's adds.
    // No spin-waits: graph-capture-safe, dispatch-order-independent.
    __syncthreads();
    if (tid == 0) {
        unsigned* ticket = (unsigned*)(ws + 1280);
        unsigned old = __hip_atomic_fetch_add(ticket, 1u, __ATOMIC_ACQ_REL,
                                              __HIP_MEMORY_SCOPE_AGENT);
        if (old == gridDim.x - 1) {            // all blocks' atomics visible
            float r = 0.0f, pq = 0.0f;
            unsigned pc = 0u;
            #pragma unroll
            for (int b = 0; b < BINS; ++b) {   // cumulative -> per-bin diff
                unsigned qraw = __hip_atomic_load((unsigned*)(ws + 128 * b),
                                __ATOMIC_RELAXED, __HIP_MEMORY_SCOPE_AGENT);
                unsigned cc   = __hip_atomic_load((unsigned*)(ws + 128 * b + 64),
                                __ATOMIC_RELAXED, __HIP_MEMORY_SCOPE_AGENT);
                float    cq  = __uint_as_float(qraw);
                unsigned cnt = cc - pc;
                float    qs  = cq - pq;
                pc = cc; pq = cq;
                if (cnt > 0u) {
                    float na = 0.75f * acc_sum[b] + 0.25f * (float)cnt;
                    r += qs / na;  // = (1/N) * sum(loss_i * N/na[bin_i])
                }
            }
            *out = r;
        }
    }
}

extern "C" void kernel_launch(void* const* d_in, const int* in_sizes, int n_in,
                              void* d_out, int out_size, void* d_ws, size_t ws_size,
                              hipStream_t stream) {
    const float* outputs = (const float*)d_in[0];  // [N,2] f32
    const int*   targets = (const int*)d_in[1];    // [N] int32
    const float* acc_sum = (const float*)d_in[2];  // [10] f32
    int n = in_sizes[1];

    ghm_zero_ws<<<1, 512, 0, stream>>>((unsigned*)d_ws);
    ghm_main<<<GRID, TPB, 0, stream>>>(outputs, targets,
                                       (unsigned char*)d_ws, acc_sum,
                                       (float*)d_out, n);
}

// Round 4
// 242.916 us; speedup vs baseline: 1.2502x; 1.2502x over previous
//
#include <hip/hip_runtime.h>

#define BINS   10
#define CSHIFT 26
#define QMASK  0x03FFFFFFu
#define QSCALE 2097152.0f        // 2^21 quanta per loss unit
#define QLN2   1453635.25f       // ln2 * 2^21: q = round(log2(1+em) * QLN2)
#define GRID   1536              // 6 blocks/CU co-resident (24 KB LDS each)
#define TPB    256
#define TILE   1024              // samples per tile: 8 KB outs + 4 KB tgt

// PRIMARY ws layout (private slots, no atomics, no zeroing needed):
//   u32  cnt[b][bid]  at word  b*GRID + bid          (b = 0..9, cumulative)
//   f32  q  [b][bid]  at word (BINS+b)*GRID + bid    (pre-scaled by 1/QSCALE)
//   total 20*GRID*4 = 122880 B; every word overwritten each launch.
// FALLBACK (ws too small): round-0 padded-atomic layout + zero kernel.

__global__ void ghm_zero_ws(unsigned* ws) {
    if (threadIdx.x < 320) ws[threadIdx.x] = 0u;   // 10 x 128 B padded slots
}

// Async global->LDS DMA, 16 B/lane. LDS dest = wave-uniform base + lane*16.
__device__ __forceinline__ void gld_lds16(const void* g, void* l) {
    __builtin_amdgcn_global_load_lds(
        (const __attribute__((address_space(1))) void*)g,
        (__attribute__((address_space(3))) void*)l, 16, 0, 0);
}

// bin b <=> D[b+1] < d <= D[b], D[b] = ln(20/b - 1); cumulative A[b] over d>Th[b].
// Packed u32: count in [31:26], quantized loss sum in [25:0].
// Per-thread bounds (<=44 samples/thread): count<=44<64; q<=44*1.45M=64M<2^26. OK.
__device__ __forceinline__ void proc1(float o0, float o1, int t, unsigned* A) {
    const float Th[BINS] = {
        2.9444390f, 2.1972246f, 1.7346011f, 1.3862944f, 1.0986123f,
        0.8472979f, 0.6190392f, 0.4054651f, 0.2006707f, 0.0f };
    float s = o0 - o1;
    float d = __int_as_float(__float_as_int(s) ^ (t << 31));  // target - other
    float em = __expf(-d);
    float qf = fmaf(__log2f(1.0f + em), QLN2, 0.5f);  // round(loss * 2^21)
    unsigned val = (unsigned)qf + (1u << CSHIFT);     // d<=0 lanes: masked below
    #pragma unroll
    for (int b = 0; b < BINS; ++b)
        A[b] += (d > Th[b]) ? val : 0u;
}

__global__ __launch_bounds__(TPB, 6)
void ghm_main(const float* __restrict__ outs,   // [n,2] f32
              const int*   __restrict__ tgt,    // [n]   i32
              unsigned char* __restrict__ ws,
              int n, int use_slots) {
    // Staging buffers union'd with epilogue scratch (never live together).
    __shared__ union {
        struct {
            unsigned char o[2][TILE * 8];      // 2 x 8 KB, global byte order
            unsigned char t[2][TILE * 4];      // 2 x 4 KB
        } st;
        struct {
            unsigned h[BINS][256];             // 10 KB
            unsigned c[BINS][16];
            float    q[BINS][16];
        } ep;
    } sh;                                      // 24 KB

    const int tid  = threadIdx.x;
    const int lane = tid & 63;
    const int wv   = tid >> 6;

    unsigned A[BINS];
    #pragma unroll
    for (int b = 0; b < BINS; ++b) A[b] = 0u;

    const int ntiles = n >> 10;                // full 1024-sample tiles

    // Stage tile -> buffer pb: per wave 2x1KB outs + 1x1KB tgt DMA issues.
    const char* outs_b = (const char*)outs;
    const char* tgt_b  = (const char*)tgt;
    #define STAGE(tile, pb)                                                     \
        do {                                                                    \
            const char* go = outs_b + ((size_t)(tile) << 13) + (wv << 11)       \
                             + (lane << 4);                                     \
            char*       lo = (char*)sh.st.o[pb] + (wv << 11);                   \
            gld_lds16(go, lo);                                                  \
            gld_lds16(go + 1024, lo + 1024);                                    \
            const char* gt = tgt_b + ((size_t)(tile) << 12) + (wv << 10)        \
                             + (lane << 4);                                     \
            gld_lds16(gt, (char*)sh.st.t[pb] + (wv << 10));                     \
        } while (0)

    int t  = blockIdx.x;
    int pb = 0;
    if (t < ntiles) STAGE(t, 0);
    __syncthreads();                           // tile t resident

    for (; t < ntiles; t += gridDim.x) {
        int tn = t + gridDim.x;
        if (tn < ntiles) STAGE(tn, pb ^ 1);    // async: overlaps consume below

        const float4* o4 = (const float4*)sh.st.o[pb];
        const int4*   t4 = (const int4*)sh.st.t[pb];
        float4 a  = o4[2 * tid];
        float4 bq = o4[2 * tid + 1];
        int4   tv = t4[tid];
        proc1(a.x,  a.y,  tv.x, A);
        proc1(a.z,  a.w,  tv.y, A);
        proc1(bq.x, bq.y, tv.z, A);
        proc1(bq.z, bq.w, tv.w, A);

        __syncthreads();                       // drains next-tile DMA too
        pb ^= 1;
    }

    // tail samples (n % 1024; zero at N=2^24) — block 0, direct from global
    int rem = ntiles << 10;
    if (blockIdx.x == 0) {
        for (int s = rem + tid; s < n; s += TPB)
            proc1(outs[2 * s], outs[2 * s + 1], tgt[s], A);
    }

    // ---- epilogue: dump packed regs, tree-reduce, 20 plain stores/block ----
    __syncthreads();                           // staging reads fully done
    #pragma unroll
    for (int b = 0; b < BINS; ++b) sh.ep.h[b][tid] = A[b];
    __syncthreads();

    if (tid < 16 * BINS) {
        int bin  = tid >> 4;
        int part = tid & 15;
        unsigned c = 0, q = 0;                 // q <= 16*64M ~ 1.0e9 < 2^32
        #pragma unroll
        for (int j = 0; j < 16; ++j) {
            unsigned v = sh.ep.h[bin][j * 16 + part];
            c += v >> CSHIFT;
            q += v & QMASK;
        }
        sh.ep.c[bin][part] = c;
        sh.ep.q[bin][part] = (float)q;
    }
    __syncthreads();
    if (tid < BINS) {
        unsigned c = 0; float q = 0.0f;
        #pragma unroll
        for (int j = 0; j < 16; ++j) { c += sh.ep.c[tid][j]; q += sh.ep.q[tid][j]; }
        if (use_slots) {                       // private slot: zero contention
            ((unsigned*)ws)[tid * GRID + blockIdx.x]        = c;
            ((float*)ws)[(BINS + tid) * GRID + blockIdx.x]  = q * (1.0f / QSCALE);
        } else if (c) {                        // fallback: padded atomics
            atomicAdd((unsigned*)(ws + 128 * tid + 64), c);
            atomicAdd((float*)   (ws + 128 * tid),      q * (1.0f / QSCALE));
        }
    }
}

// Reduce [20][GRID] private slots (123 KB, coalesced) -> scalar output.
__global__ __launch_bounds__(256)
void ghm_final2(const unsigned char* __restrict__ ws,
                const float* __restrict__ acc_sum,
                float* __restrict__ out) {
    __shared__ unsigned lc[BINS][256];         // 10 KB
    __shared__ float    lq[BINS][256];         // 10 KB
    __shared__ unsigned sc[BINS][16];
    __shared__ float    sq[BINS][16];
    const int tid = threadIdx.x;
    const unsigned* cb = (const unsigned*)ws;
    const float*    qb = (const float*)ws + (size_t)BINS * GRID;

    unsigned c[BINS]; float q[BINS];
    #pragma unroll
    for (int b = 0; b < BINS; ++b) { c[b] = 0u; q[b] = 0.0f; }
    for (int r = tid; r < GRID; r += 256) {    // 6 coalesced rounds x 20 loads
        #pragma unroll
        for (int b = 0; b < BINS; ++b) {
            c[b] += cb[b * GRID + r];
            q[b] += qb[b * GRID + r];
        }
    }
    #pragma unroll
    for (int b = 0; b < BINS; ++b) { lc[b][tid] = c[b]; lq[b][tid] = q[b]; }
    __syncthreads();

    if (tid < 16 * BINS) {
        int bin = tid >> 4, part = tid & 15;
        unsigned cc = 0u; float cq = 0.0f;
        #pragma unroll
        for (int j = 0; j < 16; ++j) {
            cc += lc[bin][j * 16 + part];
            cq += lq[bin][j * 16 + part];
        }
        sc[bin][part] = cc;
        sq[bin][part] = cq;
    }
    __syncthreads();

    if (tid == 0) {
        float r = 0.0f, pq = 0.0f;
        unsigned pc = 0u;
        #pragma unroll
        for (int b = 0; b < BINS; ++b) {       // cumulative -> per-bin diff
            unsigned cc = 0u; float cq = 0.0f;
            #pragma unroll
            for (int j = 0; j < 16; ++j) { cc += sc[b][j]; cq += sq[b][j]; }
            unsigned cnt = cc - pc;
            float    qs  = cq - pq;
            pc = cc; pq = cq;
            if (cnt > 0u) {
                float na = 0.75f * acc_sum[b] + 0.25f * (float)cnt;
                r += qs / na;    // = (1/N) * sum(loss_i * N/na[bin_i])
            }
        }
        *out = r;
    }
}

// Fallback finalization (padded-atomic layout), unchanged from round 0.
__global__ void ghm_final(const unsigned char* __restrict__ ws,
                          const float* __restrict__ acc_sum,
                          float* __restrict__ out) {
    if (threadIdx.x == 0) {
        float r = 0.0f, pq = 0.0f;
        unsigned pc = 0u;
        #pragma unroll
        for (int b = 0; b < BINS; ++b) {
            float    cq = *(const float*)   (ws + 128 * b);
            unsigned cc = *(const unsigned*)(ws + 128 * b + 64);
            unsigned cnt = cc - pc;
            float    qs  = cq - pq;
            pc = cc; pq = cq;
            if (cnt > 0u) {
                float na = 0.75f * acc_sum[b] + 0.25f * (float)cnt;
                r += qs / na;
            }
        }
        *out = r;
    }
}

extern "C" void kernel_launch(void* const* d_in, const int* in_sizes, int n_in,
                              void* d_out, int out_size, void* d_ws, size_t ws_size,
                              hipStream_t stream) {
    const float* outputs = (const float*)d_in[0];  // [N,2] f32
    const int*   targets = (const int*)d_in[1];    // [N] int32
    const float* acc_sum = (const float*)d_in[2];  // [10] f32
    int n = in_sizes[1];

    const int use_slots = (ws_size >= (size_t)2 * BINS * GRID * 4) ? 1 : 0;

    if (!use_slots)
        ghm_zero_ws<<<1, 512, 0, stream>>>((unsigned*)d_ws);
    ghm_main<<<GRID, TPB, 0, stream>>>(outputs, targets,
                                       (unsigned char*)d_ws, n, use_slots);
    if (use_slots)
        ghm_final2<<<1, 256, 0, stream>>>((const unsigned char*)d_ws, acc_sum,
                                          (float*)d_out);
    else
        ghm_final<<<1, 64, 0, stream>>>((const unsigned char*)d_ws, acc_sum,
                                        (float*)d_out);
}